// Round 1
// 548.964 us; speedup vs baseline: 1.0525x; 1.0525x over previous
//
#include <hip/hip_runtime.h>
#include <hip/hip_bf16.h>
#include <math.h>

#define NTOK 8192
#define DIM  768
#define HDIM 3072
#define NE   8
#define CAP  2560
#define AMAX 16384

typedef __bf16 bf16x8  __attribute__((ext_vector_type(8)));
typedef __bf16 bf16x2  __attribute__((ext_vector_type(2)));
typedef float  floatx4 __attribute__((ext_vector_type(4)));

typedef unsigned int u32_g __attribute__((address_space(1)));
typedef unsigned int u32_l __attribute__((address_space(3)));

__device__ __forceinline__ void gl_lds16(const void* g, void* l) {
  // 16B per lane, LDS dest = wave-uniform base + lane*16
  __builtin_amdgcn_global_load_lds((const u32_g*)g, (u32_l*)l, 16, 0, 0);
}

// gelu exact via A&S 7.1.26 erf poly (|err| < 1.5e-7)
__device__ __forceinline__ float gelu_exact(float v) {
  float z = fabsf(v) * 0.7071067811865475f;
  float t = __builtin_amdgcn_rcpf(1.0f + 0.3275911f * z);
  float p = ((((1.061405429f * t - 1.453152027f) * t + 1.421413741f) * t
              - 0.284496736f) * t + 0.254829592f) * t;
  float e = 1.0f - p * __expf(-z * z);
  e = copysignf(e, v);
  return 0.5f * v * (1.0f + e);
}

// ---------------- fused weight transpose + fp32->bf16: [E][K][N] -> [E][N][K] ----------
__global__ __launch_bounds__(256) void transpose_conv2(
    const float* __restrict__ w1, const float* __restrict__ w2,
    __bf16* __restrict__ o1, __bf16* __restrict__ o2)
{
  const int which = blockIdx.z;
  const float* src = which ? w2 : w1;
  __bf16* dst = which ? o2 : o1;
  const int Kd = which ? HDIM : DIM;
  const int Nd = which ? DIM : HDIM;
  const int e = blockIdx.y;
  const int tilesK = Kd >> 6;
  const int bk = blockIdx.x % tilesK, bn = blockIdx.x / tilesK;
  __shared__ float T[64][65];
  const float* se = src + (size_t)e * Kd * Nd;
  const int k0 = bk * 64, n0 = bn * 64;
  const int tid = threadIdx.x;
#pragma unroll
  for (int it = 0; it < 16; ++it) {
    int flat = tid + it * 256;
    int kk = flat >> 6, nn = flat & 63;
    T[kk][nn] = se[(size_t)(k0 + kk) * Nd + n0 + nn];
  }
  __syncthreads();
  const int n = tid >> 2, kg = tid & 3;
  bf16x8 v0, v1;
#pragma unroll
  for (int q = 0; q < 8; ++q) v0[q] = (__bf16)T[kg * 16 + q][n];
#pragma unroll
  for (int q = 0; q < 8; ++q) v1[q] = (__bf16)T[kg * 16 + 8 + q][n];
  __bf16* de = dst + (size_t)e * Nd * Kd + (size_t)(n0 + n) * Kd + k0 + kg * 16;
  *(bf16x8*)(de) = v0;
  *(bf16x8*)(de + 8) = v1;
}

// ---------------- router: block-aggregated dispatch (1 global atomic per expert/block) --
__global__ __launch_bounds__(256) void router_kernel(
    const float* __restrict__ x, const float* __restrict__ rw,
    int* __restrict__ list_len, double* __restrict__ imp, double* __restrict__ loadacc,
    int* __restrict__ aidx, float* __restrict__ keyarr, float* __restrict__ warr)
{
  __shared__ float Wl[NE * DIM];
  __shared__ int   lcount[NE], lbase[NE];
  __shared__ int   s_e[32][2], s_pos[32][2];
  __shared__ float s_key[32][2], s_w[32][2];
  const int tid = threadIdx.x;
  for (int i = tid; i < NE * DIM; i += 256) {
    int e = i / DIM, d = i - e * DIM;
    Wl[i] = rw[d * NE + e];
  }
  if (tid < NE) lcount[tid] = 0;
  __syncthreads();
  const int wave = tid >> 6, lane = tid & 63;
  double my_imp = 0.0, my_load = 0.0;

  for (int it = 0; it < 8; ++it) {
    const int t = wave * 8 + it;               // block-local token
    const int n = blockIdx.x * 32 + t;
    const float* xr = x + (size_t)n * DIM;
    float part[NE];
#pragma unroll
    for (int e = 0; e < NE; ++e) part[e] = 0.f;
#pragma unroll
    for (int c = 0; c < DIM / 64; ++c) {
      float xv = xr[c * 64 + lane];
#pragma unroll
      for (int e = 0; e < NE; ++e) part[e] += xv * Wl[e * DIM + c * 64 + lane];
    }
#pragma unroll
    for (int off = 32; off > 0; off >>= 1) {
#pragma unroll
      for (int e = 0; e < NE; ++e) part[e] += __shfl_xor(part[e], off);
    }
    // top-2, ties -> lower index (lax.top_k semantics)
    int e0 = 0; float v0 = part[0];
#pragma unroll
    for (int e = 1; e < NE; ++e) if (part[e] > v0) { v0 = part[e]; e0 = e; }
    int e1 = -1; float v1 = -3.4e38f;
#pragma unroll
    for (int e = 0; e < NE; ++e) if (e != e0 && part[e] > v1) { v1 = part[e]; e1 = e; }

    float pexp[NE]; float s = 0.f;
#pragma unroll
    for (int e = 0; e < NE; ++e) { pexp[e] = expf(part[e] - v0); s += pexp[e]; }
    const float inv = 1.0f / s;
    const float pr = inv;               // top-1 prob = priority
    float w1v = 0.f;
#pragma unroll
    for (int e = 0; e < NE; ++e) if (e == e1) w1v = pexp[e] * inv;

    // per-lane-expert double accumulation: lane e accumulates expert e
    float myl = 0.f, mypexp = 0.f;
#pragma unroll
    for (int e = 0; e < NE; ++e) if (lane == e) { myl = part[e]; mypexp = pexp[e]; }
    if (lane < NE) {
      my_imp  += (double)(mypexp * inv);
      // 1 - Phi((thr - logit)/NOISE_STD) = 0.5*erfc((thr-logit)/(0.125*sqrt(2)))
      my_load += (double)(0.5f * erfcf((v1 - myl) * 5.656854249492380f));
    }
    if (lane == 0) {
      int p0 = atomicAdd(&lcount[e0], 1);      // LDS atomic (cheap)
      int p1 = atomicAdd(&lcount[e1], 1);
      s_e[t][0] = e0; s_pos[t][0] = p0;
      s_key[t][0] = (float)(e0 * 4) - pr;      // e*(K+2) - score, fp32 like ref
      s_w[t][0] = pr;
      s_e[t][1] = e1; s_pos[t][1] = p1;
      s_key[t][1] = (float)(e1 * 4) - (pr - 1.0f);
      s_w[t][1] = w1v;
    }
  }
  __syncthreads();
  if (tid < NE) lbase[tid] = atomicAdd(&list_len[tid], lcount[tid]);  // 8 global atomics/block
  __syncthreads();
  if (tid < 64) {
    const int t = tid >> 1, sl = tid & 1;
    const int e = s_e[t][sl];
    const int gp = lbase[e] + s_pos[t][sl];
    const int n = blockIdx.x * 32 + t;
    aidx[e * AMAX + gp]   = n * 2 + sl;
    keyarr[e * AMAX + gp] = s_key[t][sl];
    warr[e * AMAX + gp]   = s_w[t][sl];
  }
  if (lane < NE) {
    unsafeAtomicAdd(&imp[lane], my_imp);
    unsafeAtomicAdd(&loadacc[lane], my_load);
  }
}

// ---------------- capacity keep/compact + scalar outputs -------------------------------
__global__ __launch_bounds__(256) void compact_kernel(
    const int* __restrict__ list_len, const int* __restrict__ aidx,
    const float* __restrict__ keyarr, const float* __restrict__ warr,
    int* __restrict__ dtok, float* __restrict__ dw,
    const double* __restrict__ imp, const double* __restrict__ loadacc,
    float* __restrict__ out_scalars)
{
  __shared__ float sk[6144];
  __shared__ int   sa[6144];
  const int e = blockIdx.x, tid = threadIdx.x;
  const int C = list_len[e];
  if (C <= CAP) {
    for (int t = tid; t < C; t += 256) {
      int a = aidx[e * AMAX + t];
      dtok[e * CAP + t] = a >> 1;
      dw[e * CAP + t]   = warr[e * AMAX + t];
    }
  } else {
    const bool useL = (C <= 6144);
    if (useL) {
      for (int t = tid; t < C; t += 256) { sk[t] = keyarr[e*AMAX+t]; sa[t] = aidx[e*AMAX+t]; }
      __syncthreads();
    }
    for (int t = tid; t < C; t += 256) {
      float kt = keyarr[e*AMAX+t]; int at = aidx[e*AMAX+t];
      int r = 0;
      for (int u = 0; u < C; ++u) {
        float ku = useL ? sk[u] : keyarr[e*AMAX+u];
        int   au = useL ? sa[u] : aidx[e*AMAX+u];
        if (ku < kt || (ku == kt && au < at)) ++r;
      }
      if (r < CAP) { dtok[e*CAP + r] = at >> 1; dw[e*CAP + r] = warr[e*AMAX+t]; }
    }
  }
  if (e == 0 && tid == 0) {
    double mi = 0, ml = 0;
    for (int i = 0; i < NE; ++i) { mi += imp[i]; ml += loadacc[i]; }
    mi /= NE; ml /= NE;
    double vi = 0, vl = 0;
    for (int i = 0; i < NE; ++i) {
      double di = imp[i] - mi;     vi += di * di;
      double dl = loadacc[i] - ml; vl += dl * dl;
    }
    vi /= NE; vl /= NE;
    double li = vi / (mi * mi + 1e-6), ll = vl / (ml * ml + 1e-6);
    out_scalars[0] = (float)(0.5 * (li + ll));
    int drop = 0;
    for (int i = 0; i < NE; ++i) { int c2 = list_len[i]; if (c2 > CAP) drop += c2 - CAP; }
    out_scalars[1] = (float)drop;
    for (int i = 0; i < NE; ++i) out_scalars[2 + i] = (float)list_len[i];
  }
}

// ---------------- gather kept rows into padded bf16 A buffer [E][CAP][DIM] -------------
__global__ __launch_bounds__(256) void gather_kernel(
    const float* __restrict__ x, const int* __restrict__ dtok,
    const int* __restrict__ list_len, __bf16* __restrict__ Ag)
{
  const int row  = blockIdx.x * 4 + (threadIdx.x >> 6);
  const int lane = threadIdx.x & 63;
  const int e = row / CAP, slot = row - e * CAP;
  const int kept = min(list_len[e], CAP);
  __bf16* dst = Ag + (size_t)row * DIM;
  if (slot < kept) {
    const float* srcr = x + (size_t)dtok[e * CAP + slot] * DIM;
#pragma unroll
    for (int c = 0; c < DIM / 128; ++c) {
      float2 v = *(const float2*)(srcr + c * 128 + lane * 2);
      bf16x2 o; o[0] = (__bf16)v.x; o[1] = (__bf16)v.y;
      *(bf16x2*)(dst + c * 128 + lane * 2) = o;
    }
  } else {
    bf16x2 z; z[0] = (__bf16)0.f; z[1] = (__bf16)0.f;
#pragma unroll
    for (int c = 0; c < DIM / 128; ++c) *(bf16x2*)(dst + c * 128 + lane * 2) = z;
  }
}

// ---------------- grouped GEMM: 256x256 tile, 8 waves, BK=64, 8-phase counted-vmcnt ----
// C[M,N] = A[M,K] * BT[N,K]^T per expert. Waves 2Mx4N, per-wave 128x64 (acc[8][4]).
// LDS 128KB: 2 dbuf x (A 256x64 + B 256x64) bf16, fragment-ordered chunks (16 rows x 32 k
// per 512-elem chunk, lane-linear) -> global_load_lds linear dest AND conflict-free
// ds_read_b128 (no swizzle needed; measured 0 bank conflicts with this layout).
// Per K-tile: 4 quadrant phases {ds-read subtile; stage 1 half-tile; barrier;
// setprio(1) 16 MFMA setprio(0); barrier}; vmcnt(2) only at phases 4/8 (counted, never 0
// mid-loop). Stage schedule: ph1-3 -> A1,B0,B1 of t1; ph4-7 -> tile t0+2; ph8 -> A0 of
// t0+3. Write-after-read safe: stages into a dbuf start only after its last read phase's
// closing barrier. e = xcd (expert weights + FC1's H stay in that XCD's L2).
#define BAR() do { asm volatile("" ::: "memory"); __builtin_amdgcn_s_barrier(); asm volatile("" ::: "memory"); } while (0)

#define ST_A(h, t, buf) do { \
    const __bf16* _g = gA[h] + (size_t)(t) * 64; \
    gl_lds16(_g,      &S[buf][((h) * 8 + wave) * 1024]); \
    gl_lds16(_g + 32, &S[buf][((h) * 8 + wave) * 1024 + 512]); \
  } while (0)

#define ST_B(h, t, buf) do { \
    const __bf16* _g = gB[h] + (size_t)(t) * 64; \
    gl_lds16(_g,      &S[buf][16384 + ((h) * 8 + wave) * 1024]); \
    gl_lds16(_g + 32, &S[buf][16384 + ((h) * 8 + wave) * 1024 + 512]); \
  } while (0)

#define RD_A(qm, buf) do { \
    _Pragma("unroll") \
    for (int _m = 0; _m < 4; ++_m) { \
      const int _g = wm * 8 + (qm) * 4 + _m; \
      aR[_m][0] = *(const bf16x8*)&S[buf][(_g * 2 + 0) * 512 + lane * 8]; \
      aR[_m][1] = *(const bf16x8*)&S[buf][(_g * 2 + 1) * 512 + lane * 8]; \
    } \
  } while (0)

#define RD_B(qn, buf) do { \
    _Pragma("unroll") \
    for (int _n = 0; _n < 2; ++_n) { \
      const int _g = wn * 4 + (qn) * 2 + _n; \
      bR[(qn) * 2 + _n][0] = *(const bf16x8*)&S[buf][16384 + (_g * 2 + 0) * 512 + lane * 8]; \
      bR[(qn) * 2 + _n][1] = *(const bf16x8*)&S[buf][16384 + (_g * 2 + 1) * 512 + lane * 8]; \
    } \
  } while (0)

#define MM(qm, qn) do { \
    __builtin_amdgcn_s_setprio(1); \
    _Pragma("unroll") \
    for (int _m = 0; _m < 4; ++_m) \
      _Pragma("unroll") \
      for (int _n = 0; _n < 2; ++_n) { \
        acc[(qm) * 4 + _m][(qn) * 2 + _n] = __builtin_amdgcn_mfma_f32_16x16x32_bf16( \
            aR[_m][0], bR[(qn) * 2 + _n][0], acc[(qm) * 4 + _m][(qn) * 2 + _n], 0, 0, 0); \
        acc[(qm) * 4 + _m][(qn) * 2 + _n] = __builtin_amdgcn_mfma_f32_16x16x32_bf16( \
            aR[_m][1], bR[(qn) * 2 + _n][1], acc[(qm) * 4 + _m][(qn) * 2 + _n], 0, 0, 0); \
      } \
    __builtin_amdgcn_s_setprio(0); \
  } while (0)

template<int MODE>
__global__ __launch_bounds__(512, 2) void moe_gemm8(
    const __bf16* __restrict__ Aall, const __bf16* __restrict__ BTall,
    const float* __restrict__ bias, __bf16* __restrict__ Hout,
    float* __restrict__ Out, const int* __restrict__ dtok, const float* __restrict__ dww,
    const int* __restrict__ list_len)
{
  const int Kd = MODE ? HDIM : DIM;
  const int Nd = MODE ? DIM : HDIM;
  const int numKt = Kd / 64;          // 12 (FC1) / 48 (FC2) -- both even
  const int nIter = numKt / 2;

  const int i_blk = blockIdx.x;
  const int e = i_blk & 7;            // xcd-pinned expert
  const int q = i_blk >> 3;
  const int tm = q % 10, tn = q / 10;

  const int kept = min(list_len[e], CAP);
  if (tm >= ((kept + 255) >> 8)) return;

  __shared__ __align__(16) __bf16 S[2][32768];   // 2 x (A 16K + B 16K elems) = 128 KB

  const int tid = threadIdx.x, lane = tid & 63, wave = tid >> 6;
  const int wm = wave & 1, wn = wave >> 1;
  const int m0 = tm * 256, n0 = tn * 256;
  const int lr = lane & 15, kq = lane >> 4;

  const __bf16* Abase = Aall + (size_t)e * CAP * Kd;
  const __bf16* Bbase = BTall + (size_t)e * Nd * Kd;

  const __bf16* gA[2]; const __bf16* gB[2];
#pragma unroll
  for (int h = 0; h < 2; ++h) {
    gA[h] = Abase + (size_t)(m0 + (h * 8 + wave) * 16 + lr) * Kd + kq * 8;
    gB[h] = Bbase + (size_t)(n0 + (h * 8 + wave) * 16 + lr) * Kd + kq * 8;
  }

  floatx4 acc[8][4];
#pragma unroll
  for (int i = 0; i < 8; ++i)
#pragma unroll
    for (int j = 0; j < 4; ++j) acc[i][j] = (floatx4)0.f;

  bf16x8 aR[4][2], bR[4][2];

  // prologue: tile0 fully (dbuf0) + A0 of tile1 (dbuf1); drain tile0, keep 1 half in flight
  ST_A(0, 0, 0); ST_A(1, 0, 0); ST_B(0, 0, 0); ST_B(1, 0, 0);
  ST_A(0, 1, 1);
  __builtin_amdgcn_s_waitcnt(0x0F72);   // vmcnt(2)
  BAR();

#pragma unroll 1
  for (int i = 0; i < nIter; ++i) {
    const int t0 = 2 * i;
    const bool more = (i < nIter - 1);

    // ---- K-tile t0 (dbuf0) ----
    // ph1: quad(qm0,qn0)
    RD_A(0, 0); RD_B(0, 0);
    ST_A(1, t0 + 1, 1);
    BAR(); MM(0, 0); BAR();
    // ph2: quad(qm0,qn1)
    RD_B(1, 0);
    ST_B(0, t0 + 1, 1);
    BAR(); MM(0, 1); BAR();
    // ph3: quad(qm1,qn1)
    RD_A(1, 0);
    ST_B(1, t0 + 1, 1);
    BAR(); MM(1, 1); BAR();
    // ph4: quad(qm1,qn0) -- no reads; stage A0(t0+2); drain tile t0+1's halves
    if (more) {
      ST_A(0, t0 + 2, 0);
      __builtin_amdgcn_s_waitcnt(0x0F72);   // vmcnt(2): t1 halves landed, A0(t0+2) in flight
    } else {
      __builtin_amdgcn_s_waitcnt(0x0F70);   // vmcnt(0): final drain before last K-tile
    }
    BAR(); MM(1, 0); BAR();

    // ---- K-tile t0+1 (dbuf1) ----
    // ph5
    RD_A(0, 1); RD_B(0, 1);
    if (more) ST_A(1, t0 + 2, 0);
    BAR(); MM(0, 0); BAR();
    // ph6
    RD_B(1, 1);
    if (more) ST_B(0, t0 + 2, 0);
    BAR(); MM(0, 1); BAR();
    // ph7
    RD_A(1, 1);
    if (more) ST_B(1, t0 + 2, 0);
    BAR(); MM(1, 1); BAR();
    // ph8: stage A0(t0+3); drain tile t0+2's halves
    if (more) {
      ST_A(0, t0 + 3, 1);
      __builtin_amdgcn_s_waitcnt(0x0F72);   // vmcnt(2)
    } else {
      __builtin_amdgcn_s_waitcnt(0x0F70);
    }
    BAR(); MM(1, 0); BAR();
  }

  // ---- epilogue ---- C/D layout: col=lane&15, row=(lane>>4)*4+reg
  const int quad = lane >> 4, lcol = lane & 15;
  float bcol[4];
#pragma unroll
  for (int n = 0; n < 4; ++n)
    bcol[n] = bias[e * Nd + n0 + wn * 64 + n * 16 + lcol];

  if (MODE == 0) {
#pragma unroll
    for (int m = 0; m < 8; ++m) {
#pragma unroll
      for (int r = 0; r < 4; ++r) {
        const int row = m0 + wm * 128 + m * 16 + quad * 4 + r;
        __bf16* hrow = Hout + ((size_t)(e * CAP + row)) * Nd + n0 + wn * 64;
#pragma unroll
        for (int n = 0; n < 4; ++n)
          hrow[n * 16 + lcol] = (__bf16)gelu_exact(acc[m][n][r] + bcol[n]);
      }
    }
  } else {
#pragma unroll
    for (int m = 0; m < 8; ++m) {
#pragma unroll
      for (int r = 0; r < 4; ++r) {
        const int row = m0 + wm * 128 + m * 16 + quad * 4 + r;
        const float w = dww[e * CAP + row];
        if (w != 0.0f) {
          const int tok = dtok[e * CAP + row];
          float* orow = Out + (size_t)tok * DIM + n0 + wn * 64;
#pragma unroll
          for (int n = 0; n < 4; ++n)
            unsafeAtomicAdd(&orow[n * 16 + lcol], w * (acc[m][n][r] + bcol[n]));
        }
      }
    }
  }
}

#undef BAR
#undef ST_A
#undef ST_B
#undef RD_A
#undef RD_B
#undef MM

extern "C" void kernel_launch(void* const* d_in, const int* in_sizes, int n_in,
                              void* d_out, int out_size, void* d_ws, size_t ws_size,
                              hipStream_t stream) {
  (void)in_sizes; (void)n_in; (void)out_size; (void)ws_size;
  const float* x  = (const float*)d_in[0];
  const float* rw = (const float*)d_in[1];
  const float* w1 = (const float*)d_in[2];
  const float* b1 = (const float*)d_in[3];
  const float* w2 = (const float*)d_in[4];
  const float* b2 = (const float*)d_in[5];
  float* out = (float*)d_out;
  char* ws = (char*)d_ws;

  int*    list_len = (int*)(ws + 0);
  double* imp      = (double*)(ws + 64);
  double* loadacc  = (double*)(ws + 128);
  int*    dtok     = (int*)(ws + 256);
  float*  dw       = (float*)(ws + 256 + 81920);
  int*    aidx     = (int*)(ws + 164096);
  float*  keyarr   = (float*)(ws + 164096 + 524288);
  float*  warr     = (float*)(ws + 164096 + 1048576);
  __bf16* W1T      = (__bf16*)(ws + 2097152);
  __bf16* W2T      = (__bf16*)(ws + 2097152 + 37748736);
  __bf16* Ag       = (__bf16*)(ws + 2097152 + 2 * 37748736);
  __bf16* hbuf     = (__bf16*)(ws + 2097152 + 2 * 37748736 + 31457280);

  hipMemsetAsync(d_out, 0, (size_t)NTOK * DIM * sizeof(float), stream);
  hipMemsetAsync(ws, 0, 164096, stream);

  transpose_conv2<<<dim3(576, 8, 2), 256, 0, stream>>>(w1, w2, W1T, W2T);
  router_kernel<<<NTOK / 32, 256, 0, stream>>>(x, rw, list_len, imp, loadacc, aidx, keyarr, warr);
  compact_kernel<<<NE, 256, 0, stream>>>(list_len, aidx, keyarr, warr, dtok, dw, imp, loadacc,
                                         out + (size_t)NTOK * DIM);
  gather_kernel<<<(NE * CAP) / 4, 256, 0, stream>>>(x, dtok, list_len, Ag);
  // FC1: 8 xcd x (10 tm x 12 tn) = 960 blocks, 512 thr, 128KB LDS (1 block/CU)
  moe_gemm8<0><<<NE * 10 * (HDIM / 256), 512, 0, stream>>>(
      Ag, W1T, b1, hbuf, nullptr, nullptr, nullptr, list_len);
  // FC2: 8 xcd x (10 tm x 3 tn) = 240 blocks, no split-K (half the atomics)
  moe_gemm8<1><<<NE * 10 * (DIM / 256), 512, 0, stream>>>(
      hbuf, W2T, b2, nullptr, out, dtok, dw, list_len);
}

// Round 2
// 533.364 us; speedup vs baseline: 1.0833x; 1.0292x over previous
//
#include <hip/hip_runtime.h>
#include <hip/hip_bf16.h>
#include <math.h>

#define NTOK 8192
#define DIM  768
#define HDIM 3072
#define NE   8
#define CAP  2560
#define AMAX 16384

typedef __bf16 bf16x8  __attribute__((ext_vector_type(8)));
typedef __bf16 bf16x2  __attribute__((ext_vector_type(2)));
typedef float  floatx4 __attribute__((ext_vector_type(4)));

typedef unsigned int u32_g __attribute__((address_space(1)));
typedef unsigned int u32_l __attribute__((address_space(3)));

__device__ __forceinline__ void gl_lds16(const void* g, void* l) {
  // 16B per lane, LDS dest = wave-uniform base + lane*16
  __builtin_amdgcn_global_load_lds((const u32_g*)g, (u32_l*)l, 16, 0, 0);
}

// gelu exact via A&S 7.1.26 erf poly (|err| < 1.5e-7)
__device__ __forceinline__ float gelu_exact(float v) {
  float z = fabsf(v) * 0.7071067811865475f;
  float t = __builtin_amdgcn_rcpf(1.0f + 0.3275911f * z);
  float p = ((((1.061405429f * t - 1.453152027f) * t + 1.421413741f) * t
              - 0.284496736f) * t + 0.254829592f) * t;
  float e = 1.0f - p * __expf(-z * z);
  e = copysignf(e, v);
  return 0.5f * v * (1.0f + e);
}

// ---------------- fused weight transpose + fp32->bf16: [E][K][N] -> [E][N][K] ----------
__global__ __launch_bounds__(256) void transpose_conv2(
    const float* __restrict__ w1, const float* __restrict__ w2,
    __bf16* __restrict__ o1, __bf16* __restrict__ o2)
{
  const int which = blockIdx.z;
  const float* src = which ? w2 : w1;
  __bf16* dst = which ? o2 : o1;
  const int Kd = which ? HDIM : DIM;
  const int Nd = which ? DIM : HDIM;
  const int e = blockIdx.y;
  const int tilesK = Kd >> 6;
  const int bk = blockIdx.x % tilesK, bn = blockIdx.x / tilesK;
  __shared__ float T[64][65];
  const float* se = src + (size_t)e * Kd * Nd;
  const int k0 = bk * 64, n0 = bn * 64;
  const int tid = threadIdx.x;
#pragma unroll
  for (int it = 0; it < 16; ++it) {
    int flat = tid + it * 256;
    int kk = flat >> 6, nn = flat & 63;
    T[kk][nn] = se[(size_t)(k0 + kk) * Nd + n0 + nn];
  }
  __syncthreads();
  const int n = tid >> 2, kg = tid & 3;
  bf16x8 v0, v1;
#pragma unroll
  for (int q = 0; q < 8; ++q) v0[q] = (__bf16)T[kg * 16 + q][n];
#pragma unroll
  for (int q = 0; q < 8; ++q) v1[q] = (__bf16)T[kg * 16 + 8 + q][n];
  __bf16* de = dst + (size_t)e * Nd * Kd + (size_t)(n0 + n) * Kd + k0 + kg * 16;
  *(bf16x8*)(de) = v0;
  *(bf16x8*)(de + 8) = v1;
}

// ---------------- router: block-aggregated dispatch (1 global atomic per expert/block) --
__global__ __launch_bounds__(256) void router_kernel(
    const float* __restrict__ x, const float* __restrict__ rw,
    int* __restrict__ list_len, double* __restrict__ imp, double* __restrict__ loadacc,
    int* __restrict__ aidx, float* __restrict__ keyarr, float* __restrict__ warr)
{
  __shared__ float Wl[NE * DIM];
  __shared__ int   lcount[NE], lbase[NE];
  __shared__ int   s_e[32][2], s_pos[32][2];
  __shared__ float s_key[32][2], s_w[32][2];
  const int tid = threadIdx.x;
  for (int i = tid; i < NE * DIM; i += 256) {
    int e = i / DIM, d = i - e * DIM;
    Wl[i] = rw[d * NE + e];
  }
  if (tid < NE) lcount[tid] = 0;
  __syncthreads();
  const int wave = tid >> 6, lane = tid & 63;
  double my_imp = 0.0, my_load = 0.0;

  for (int it = 0; it < 8; ++it) {
    const int t = wave * 8 + it;               // block-local token
    const int n = blockIdx.x * 32 + t;
    const float* xr = x + (size_t)n * DIM;
    float part[NE];
#pragma unroll
    for (int e = 0; e < NE; ++e) part[e] = 0.f;
#pragma unroll
    for (int c = 0; c < DIM / 64; ++c) {
      float xv = xr[c * 64 + lane];
#pragma unroll
      for (int e = 0; e < NE; ++e) part[e] += xv * Wl[e * DIM + c * 64 + lane];
    }
#pragma unroll
    for (int off = 32; off > 0; off >>= 1) {
#pragma unroll
      for (int e = 0; e < NE; ++e) part[e] += __shfl_xor(part[e], off);
    }
    // top-2, ties -> lower index (lax.top_k semantics)
    int e0 = 0; float v0 = part[0];
#pragma unroll
    for (int e = 1; e < NE; ++e) if (part[e] > v0) { v0 = part[e]; e0 = e; }
    int e1 = -1; float v1 = -3.4e38f;
#pragma unroll
    for (int e = 0; e < NE; ++e) if (e != e0 && part[e] > v1) { v1 = part[e]; e1 = e; }

    float pexp[NE]; float s = 0.f;
#pragma unroll
    for (int e = 0; e < NE; ++e) { pexp[e] = expf(part[e] - v0); s += pexp[e]; }
    const float inv = 1.0f / s;
    const float pr = inv;               // top-1 prob = priority
    float w1v = 0.f;
#pragma unroll
    for (int e = 0; e < NE; ++e) if (e == e1) w1v = pexp[e] * inv;

    // per-lane-expert double accumulation: lane e accumulates expert e
    float myl = 0.f, mypexp = 0.f;
#pragma unroll
    for (int e = 0; e < NE; ++e) if (lane == e) { myl = part[e]; mypexp = pexp[e]; }
    if (lane < NE) {
      my_imp  += (double)(mypexp * inv);
      // 1 - Phi((thr - logit)/NOISE_STD) = 0.5*erfc((thr-logit)/(0.125*sqrt(2)))
      my_load += (double)(0.5f * erfcf((v1 - myl) * 5.656854249492380f));
    }
    if (lane == 0) {
      int p0 = atomicAdd(&lcount[e0], 1);      // LDS atomic (cheap)
      int p1 = atomicAdd(&lcount[e1], 1);
      s_e[t][0] = e0; s_pos[t][0] = p0;
      s_key[t][0] = (float)(e0 * 4) - pr;      // e*(K+2) - score, fp32 like ref
      s_w[t][0] = pr;
      s_e[t][1] = e1; s_pos[t][1] = p1;
      s_key[t][1] = (float)(e1 * 4) - (pr - 1.0f);
      s_w[t][1] = w1v;
    }
  }
  __syncthreads();
  if (tid < NE) lbase[tid] = atomicAdd(&list_len[tid], lcount[tid]);  // 8 global atomics/block
  __syncthreads();
  if (tid < 64) {
    const int t = tid >> 1, sl = tid & 1;
    const int e = s_e[t][sl];
    const int gp = lbase[e] + s_pos[t][sl];
    const int n = blockIdx.x * 32 + t;
    aidx[e * AMAX + gp]   = n * 2 + sl;
    keyarr[e * AMAX + gp] = s_key[t][sl];
    warr[e * AMAX + gp]   = s_w[t][sl];
  }
  if (lane < NE) {
    unsafeAtomicAdd(&imp[lane], my_imp);
    unsafeAtomicAdd(&loadacc[lane], my_load);
  }
}

// ---------------- capacity keep/compact + scalar outputs -------------------------------
__global__ __launch_bounds__(256) void compact_kernel(
    const int* __restrict__ list_len, const int* __restrict__ aidx,
    const float* __restrict__ keyarr, const float* __restrict__ warr,
    int* __restrict__ dtok, float* __restrict__ dw,
    const double* __restrict__ imp, const double* __restrict__ loadacc,
    float* __restrict__ out_scalars)
{
  __shared__ float sk[6144];
  __shared__ int   sa[6144];
  const int e = blockIdx.x, tid = threadIdx.x;
  const int C = list_len[e];
  if (C <= CAP) {
    for (int t = tid; t < C; t += 256) {
      int a = aidx[e * AMAX + t];
      dtok[e * CAP + t] = a >> 1;
      dw[e * CAP + t]   = warr[e * AMAX + t];
    }
  } else {
    const bool useL = (C <= 6144);
    if (useL) {
      for (int t = tid; t < C; t += 256) { sk[t] = keyarr[e*AMAX+t]; sa[t] = aidx[e*AMAX+t]; }
      __syncthreads();
    }
    for (int t = tid; t < C; t += 256) {
      float kt = keyarr[e*AMAX+t]; int at = aidx[e*AMAX+t];
      int r = 0;
      for (int u = 0; u < C; ++u) {
        float ku = useL ? sk[u] : keyarr[e*AMAX+u];
        int   au = useL ? sa[u] : aidx[e*AMAX+u];
        if (ku < kt || (ku == kt && au < at)) ++r;
      }
      if (r < CAP) { dtok[e*CAP + r] = at >> 1; dw[e*CAP + r] = warr[e*AMAX+t]; }
    }
  }
  if (e == 0 && tid == 0) {
    double mi = 0, ml = 0;
    for (int i = 0; i < NE; ++i) { mi += imp[i]; ml += loadacc[i]; }
    mi /= NE; ml /= NE;
    double vi = 0, vl = 0;
    for (int i = 0; i < NE; ++i) {
      double di = imp[i] - mi;     vi += di * di;
      double dl = loadacc[i] - ml; vl += dl * dl;
    }
    vi /= NE; vl /= NE;
    double li = vi / (mi * mi + 1e-6), ll = vl / (ml * ml + 1e-6);
    out_scalars[0] = (float)(0.5 * (li + ll));
    int drop = 0;
    for (int i = 0; i < NE; ++i) { int c2 = list_len[i]; if (c2 > CAP) drop += c2 - CAP; }
    out_scalars[1] = (float)drop;
    for (int i = 0; i < NE; ++i) out_scalars[2 + i] = (float)list_len[i];
  }
}

// ---------------- gather kept rows into padded bf16 A buffer [E][CAP][DIM] -------------
__global__ __launch_bounds__(256) void gather_kernel(
    const float* __restrict__ x, const int* __restrict__ dtok,
    const int* __restrict__ list_len, __bf16* __restrict__ Ag)
{
  const int row  = blockIdx.x * 4 + (threadIdx.x >> 6);
  const int lane = threadIdx.x & 63;
  const int e = row / CAP, slot = row - e * CAP;
  const int kept = min(list_len[e], CAP);
  __bf16* dst = Ag + (size_t)row * DIM;
  if (slot < kept) {
    const float* srcr = x + (size_t)dtok[e * CAP + slot] * DIM;
#pragma unroll
    for (int c = 0; c < DIM / 128; ++c) {
      float2 v = *(const float2*)(srcr + c * 128 + lane * 2);
      bf16x2 o; o[0] = (__bf16)v.x; o[1] = (__bf16)v.y;
      *(bf16x2*)(dst + c * 128 + lane * 2) = o;
    }
  } else {
    bf16x2 z; z[0] = (__bf16)0.f; z[1] = (__bf16)0.f;
#pragma unroll
    for (int c = 0; c < DIM / 128; ++c) *(bf16x2*)(dst + c * 128 + lane * 2) = z;
  }
}

// ---------------- grouped GEMM: 256x256 tile, 8 waves, BK=32, quad-buffer deep pipe ----
// C[M,N] = A[M,K] * BT[N,K]^T per expert. Waves 2Mx4N, per-wave 128x64 (acc[8][4]).
// LDS 128KB: 4 bufs x (A 256x32 + B 256x32) bf16, fragment-ordered 512-elem chunks
// (16 rows x 32 k, lane-linear: lane l -> row l&15, k (l>>4)*8) -> global_load_lds
// linear dest AND conflict-free ds_read_b128 (0 conflicts measured with this layout).
// Per K-tile t (buf t&3), 2 phases:
//   phA: RD A-half0 (4 b128) + all B (4 b128); ST_A(t+3); bar; 16 MFMA; bar
//   phB: RD A-half1 (4 b128);                  ST_B(t+3); vmcnt(8); bar; 16 MFMA; bar
// vmcnt(8) leaves tiles t+2,t+3 (8 loads/wave) in flight and drains t+1, whose loads
// were issued 5-6 phases earlier (~3600 cyc) -> HBM latency fully covered; never
// drains to 0 mid-loop (tail: 8 -> 4 -> 0). e = xcd (weights + H L2-local per XCD).
#define BAR() do { asm volatile("" ::: "memory"); __builtin_amdgcn_s_barrier(); asm volatile("" ::: "memory"); } while (0)

#define ST_A(t, bf) do { \
    gl_lds16(gA0 + (size_t)(t) * 32, &S[bf][(wave * 2 + 0) * 512]); \
    gl_lds16(gA1 + (size_t)(t) * 32, &S[bf][(wave * 2 + 1) * 512]); \
  } while (0)

#define ST_B(t, bf) do { \
    gl_lds16(gB0 + (size_t)(t) * 32, &S[bf][8192 + (wave * 2 + 0) * 512]); \
    gl_lds16(gB1 + (size_t)(t) * 32, &S[bf][8192 + (wave * 2 + 1) * 512]); \
  } while (0)

#define RD_A(half, bf) do { \
    _Pragma("unroll") \
    for (int _m = 0; _m < 4; ++_m) \
      aR[_m] = *(const bf16x8*)&S[bf][(wm * 8 + (half) * 4 + _m) * 512 + lane * 8]; \
  } while (0)

#define RD_B(bf) do { \
    _Pragma("unroll") \
    for (int _n = 0; _n < 4; ++_n) \
      bR[_n] = *(const bf16x8*)&S[bf][8192 + (wn * 4 + _n) * 512 + lane * 8]; \
  } while (0)

#define MM(qm) do { \
    __builtin_amdgcn_s_setprio(1); \
    _Pragma("unroll") \
    for (int _m = 0; _m < 4; ++_m) \
      _Pragma("unroll") \
      for (int _n = 0; _n < 4; ++_n) \
        acc[(qm) * 4 + _m][_n] = __builtin_amdgcn_mfma_f32_16x16x32_bf16( \
            aR[_m], bR[_n], acc[(qm) * 4 + _m][_n], 0, 0, 0); \
    __builtin_amdgcn_s_setprio(0); \
  } while (0)

template<int MODE>
__global__ __launch_bounds__(512, 2) void moe_gemm8(
    const __bf16* __restrict__ Aall, const __bf16* __restrict__ BTall,
    const float* __restrict__ bias, __bf16* __restrict__ Hout,
    float* __restrict__ Out, const int* __restrict__ dtok, const float* __restrict__ dww,
    const int* __restrict__ list_len)
{
  const int Kd = MODE ? HDIM : DIM;
  const int Nd = MODE ? DIM : HDIM;
  const int nT = Kd / 32;             // 24 (FC1) / 96 (FC2)

  const int i_blk = blockIdx.x;
  const int e = i_blk & 7;            // xcd-pinned expert
  const int q = i_blk >> 3;
  const int tm = q % 10, tn = q / 10;

  const int kept = min(list_len[e], CAP);
  if (tm >= ((kept + 255) >> 8)) return;

  __shared__ __align__(16) __bf16 S[4][16384];   // 4 bufs x (A 8K + B 8K elems) = 128 KB

  const int tid = threadIdx.x, lane = tid & 63, wave = tid >> 6;
  const int wm = wave & 1, wn = wave >> 1;
  const int m0 = tm * 256, n0 = tn * 256;
  const int lr = lane & 15, kq = lane >> 4;

  const __bf16* Abase = Aall + (size_t)e * CAP * Kd;
  const __bf16* Bbase = BTall + (size_t)e * Nd * Kd;

  const __bf16* gA0 = Abase + (size_t)(m0 + (wave * 2 + 0) * 16 + lr) * Kd + kq * 8;
  const __bf16* gA1 = Abase + (size_t)(m0 + (wave * 2 + 1) * 16 + lr) * Kd + kq * 8;
  const __bf16* gB0 = Bbase + (size_t)(n0 + (wave * 2 + 0) * 16 + lr) * Kd + kq * 8;
  const __bf16* gB1 = Bbase + (size_t)(n0 + (wave * 2 + 1) * 16 + lr) * Kd + kq * 8;

  floatx4 acc[8][4];
#pragma unroll
  for (int i = 0; i < 8; ++i)
#pragma unroll
    for (int j = 0; j < 4; ++j) acc[i][j] = (floatx4)0.f;

  bf16x8 aR[4], bR[4];

  // prologue: stage tiles 0,1,2; wait tile0 (leave t1,t2 = 8 loads in flight)
  ST_A(0, 0); ST_B(0, 0);
  ST_A(1, 1); ST_B(1, 1);
  ST_A(2, 2); ST_B(2, 2);
  __builtin_amdgcn_s_waitcnt(0x0F78);   // vmcnt(8)
  BAR();

#pragma unroll 1
  for (int t = 0; t <= nT - 4; ++t) {
    const int bt = t & 3, bs = (t + 3) & 3;
    // phA
    RD_A(0, bt); RD_B(bt);
    ST_A(t + 3, bs);
    BAR(); MM(0); BAR();
    // phB
    RD_A(1, bt);
    ST_B(t + 3, bs);
    __builtin_amdgcn_s_waitcnt(0x0F78); // vmcnt(8): t+1 landed, t+2/t+3 stay in flight
    BAR(); MM(1); BAR();
  }

  // tail: tiles nT-3, nT-2, nT-1 (drain 8 -> 4 -> 0, no new stages)
  {
    int bt = (nT - 3) & 3;
    RD_A(0, bt); RD_B(bt); BAR(); MM(0); BAR();
    RD_A(1, bt);
    __builtin_amdgcn_s_waitcnt(0x0F74); // vmcnt(4): tile nT-2 landed
    BAR(); MM(1); BAR();

    bt = (nT - 2) & 3;
    RD_A(0, bt); RD_B(bt); BAR(); MM(0); BAR();
    RD_A(1, bt);
    __builtin_amdgcn_s_waitcnt(0x0F70); // vmcnt(0): tile nT-1 landed
    BAR(); MM(1); BAR();

    bt = (nT - 1) & 3;
    RD_A(0, bt); RD_B(bt); MM(0);
    RD_A(1, bt); MM(1);                 // no pending LDS writes: no barriers needed
  }

  // ---- epilogue ---- C/D layout: col=lane&15, row=(lane>>4)*4+reg
  const int quad = lane >> 4, lcol = lane & 15;
  float bcol[4];
#pragma unroll
  for (int n = 0; n < 4; ++n)
    bcol[n] = bias[e * Nd + n0 + wn * 64 + n * 16 + lcol];

  if (MODE == 0) {
#pragma unroll
    for (int m = 0; m < 8; ++m) {
#pragma unroll
      for (int r = 0; r < 4; ++r) {
        const int row = m0 + wm * 128 + m * 16 + quad * 4 + r;
        __bf16* hrow = Hout + ((size_t)(e * CAP + row)) * Nd + n0 + wn * 64;
#pragma unroll
        for (int n = 0; n < 4; ++n)
          hrow[n * 16 + lcol] = (__bf16)gelu_exact(acc[m][n][r] + bcol[n]);
      }
    }
  } else {
#pragma unroll
    for (int m = 0; m < 8; ++m) {
#pragma unroll
      for (int r = 0; r < 4; ++r) {
        const int row = m0 + wm * 128 + m * 16 + quad * 4 + r;
        const float w = dww[e * CAP + row];
        if (w != 0.0f) {
          const int tok = dtok[e * CAP + row];
          float* orow = Out + (size_t)tok * DIM + n0 + wn * 64;
#pragma unroll
          for (int n = 0; n < 4; ++n)
            unsafeAtomicAdd(&orow[n * 16 + lcol], w * (acc[m][n][r] + bcol[n]));
        }
      }
    }
  }
}

#undef BAR
#undef ST_A
#undef ST_B
#undef RD_A
#undef RD_B
#undef MM

extern "C" void kernel_launch(void* const* d_in, const int* in_sizes, int n_in,
                              void* d_out, int out_size, void* d_ws, size_t ws_size,
                              hipStream_t stream) {
  (void)in_sizes; (void)n_in; (void)out_size; (void)ws_size;
  const float* x  = (const float*)d_in[0];
  const float* rw = (const float*)d_in[1];
  const float* w1 = (const float*)d_in[2];
  const float* b1 = (const float*)d_in[3];
  const float* w2 = (const float*)d_in[4];
  const float* b2 = (const float*)d_in[5];
  float* out = (float*)d_out;
  char* ws = (char*)d_ws;

  int*    list_len = (int*)(ws + 0);
  double* imp      = (double*)(ws + 64);
  double* loadacc  = (double*)(ws + 128);
  int*    dtok     = (int*)(ws + 256);
  float*  dw       = (float*)(ws + 256 + 81920);
  int*    aidx     = (int*)(ws + 164096);
  float*  keyarr   = (float*)(ws + 164096 + 524288);
  float*  warr     = (float*)(ws + 164096 + 1048576);
  __bf16* W1T      = (__bf16*)(ws + 2097152);
  __bf16* W2T      = (__bf16*)(ws + 2097152 + 37748736);
  __bf16* Ag       = (__bf16*)(ws + 2097152 + 2 * 37748736);
  __bf16* hbuf     = (__bf16*)(ws + 2097152 + 2 * 37748736 + 31457280);

  hipMemsetAsync(d_out, 0, (size_t)NTOK * DIM * sizeof(float), stream);
  hipMemsetAsync(ws, 0, 164096, stream);

  transpose_conv2<<<dim3(576, 8, 2), 256, 0, stream>>>(w1, w2, W1T, W2T);
  router_kernel<<<NTOK / 32, 256, 0, stream>>>(x, rw, list_len, imp, loadacc, aidx, keyarr, warr);
  compact_kernel<<<NE, 256, 0, stream>>>(list_len, aidx, keyarr, warr, dtok, dw, imp, loadacc,
                                         out + (size_t)NTOK * DIM);
  gather_kernel<<<(NE * CAP) / 4, 256, 0, stream>>>(x, dtok, list_len, Ag);
  // FC1: 8 xcd x (10 tm x 12 tn) = 960 blocks, 512 thr, 128KB LDS (1 block/CU)
  moe_gemm8<0><<<NE * 10 * (HDIM / 256), 512, 0, stream>>>(
      Ag, W1T, b1, hbuf, nullptr, nullptr, nullptr, list_len);
  // FC2: 8 xcd x (10 tm x 3 tn) = 240 blocks, no split-K (half the atomics)
  moe_gemm8<1><<<NE * 10 * (DIM / 256), 512, 0, stream>>>(
      hbuf, W2T, b2, nullptr, out, dtok, dw, list_len);
}